// Round 10
// baseline (44386.414 us; speedup 1.0000x reference)
//
#include <hip/hip_runtime.h>
#include <cstdint>
#include <cstddef>

#define B_ 32
#define L_ 1024
#define I_ 1024
#define H_ 1024
#define G3_ 3072
#define G3I ((size_t)G3_ * I_)
#define NBLK 128

typedef short short8 __attribute__((ext_vector_type(8)));
typedef float floatx4 __attribute__((ext_vector_type(4)));

__device__ __forceinline__ unsigned short f2bf_rne(float f) {
    unsigned u = __float_as_uint(f);
    unsigned r = (u + 0x7fffu + ((u >> 16) & 1u)) >> 16;
    return (unsigned short)r;
}
__device__ __forceinline__ float bf2f(unsigned short u) {
    return __uint_as_float(((unsigned)u) << 16);
}

// coherence-point 16B load (bypasses L1/L2; serviced fresh by Infinity Cache).
// PROVEN transport (rounds 5/8/9).
__device__ __forceinline__ short8 ld16_sc(const unsigned short* p) {
    short8 r;
    asm volatile("global_load_dwordx4 %0, %1, off sc0 sc1"
                 : "=v"(r) : "v"(p) : "memory");
    return r;
}

#define VM_WAIT(N) do { \
    asm volatile("s_waitcnt vmcnt(" #N ")" ::: "memory"); \
    __builtin_amdgcn_sched_barrier(0); \
} while (0)

// ---- prep: transpose weights [K][3H] -> [col][K], split bf16 hi/lo ---------
__global__ __launch_bounds__(256) void k_trans_w(const float* __restrict__ Wi,
                                                 const float* __restrict__ Wh,
                                                 unsigned short* __restrict__ wt) {
    int mat = blockIdx.y;            // 0=Wi0 1=Wh0 2=Wi1 3=Wh1
    int layer = mat >> 1, ish = mat & 1;
    const float* src = (ish ? Wh : Wi) + (size_t)layer * I_ * G3_;
    unsigned short* dhi = wt + (size_t)mat * 2u * G3I;
    unsigned short* dlo = dhi + G3I;
    int kt = blockIdx.x & 15;        // 16 k-tiles of 64
    int ct = blockIdx.x >> 4;        // 48 col-tiles of 64
    __shared__ float tile[64][65];
    int tid = threadIdx.x;
    int c_in = tid & 63, kr = tid >> 6;
    for (int pass = 0; pass < 16; ++pass) {
        int k = kt * 64 + pass * 4 + kr;
        tile[pass * 4 + kr][c_in] = src[(size_t)k * G3_ + ct * 64 + c_in];
    }
    __syncthreads();
    int k_out = tid & 63, cr = tid >> 6;
    for (int pass = 0; pass < 16; ++pass) {
        int c = ct * 64 + pass * 4 + cr;
        float f = tile[k_out][pass * 4 + cr];
        unsigned short hb = f2bf_rne(f);
        size_t o = (size_t)c * I_ + kt * 64 + k_out;
        dhi[o] = hb;
        dlo[o] = f2bf_rne(f - bf2f(hb));
    }
}

// ---- precompute gi0 = x @ Wi0 for ALL timesteps (one big GEMM) -------------
__global__ __launch_bounds__(512) void k_gi0(const float* __restrict__ xf,
                                             const unsigned short* __restrict__ wt,
                                             float* __restrict__ gi0) {
    int mt = blockIdx.x;             // 512 m-tiles of 64 rows
    int nt = blockIdx.y;             // 48 n-tiles of 64 cols
    int tid = threadIdx.x, wave = tid >> 6, lane = tid & 63;
    int mq = wave & 3, npair = wave >> 2;
    int arow = lane & 15, klq = (lane >> 4) * 8;
    const unsigned short* wHi = wt;  // Wi0 hi
    const unsigned short* wLo = wt + G3I;
    size_t abase = ((size_t)(mt * 64 + mq * 16 + arow)) * I_;
    int c0 = nt * 64 + npair * 32 + (lane & 15);
    floatx4 acc[2] = {};
    for (int it = 0; it < 32; ++it) {
        int kk = it * 32 + klq;
        float4 f0 = *(const float4*)(xf + abase + kk);
        float4 f1 = *(const float4*)(xf + abase + kk + 4);
        short8 ah, al;
        {
            float v0 = f0.x, v1 = f0.y, v2 = f0.z, v3 = f0.w;
            float v4 = f1.x, v5 = f1.y, v6 = f1.z, v7 = f1.w;
            unsigned short hb;
            hb = f2bf_rne(v0); ah[0] = (short)hb; al[0] = (short)f2bf_rne(v0 - bf2f(hb));
            hb = f2bf_rne(v1); ah[1] = (short)hb; al[1] = (short)f2bf_rne(v1 - bf2f(hb));
            hb = f2bf_rne(v2); ah[2] = (short)hb; al[2] = (short)f2bf_rne(v2 - bf2f(hb));
            hb = f2bf_rne(v3); ah[3] = (short)hb; al[3] = (short)f2bf_rne(v3 - bf2f(hb));
            hb = f2bf_rne(v4); ah[4] = (short)hb; al[4] = (short)f2bf_rne(v4 - bf2f(hb));
            hb = f2bf_rne(v5); ah[5] = (short)hb; al[5] = (short)f2bf_rne(v5 - bf2f(hb));
            hb = f2bf_rne(v6); ah[6] = (short)hb; al[6] = (short)f2bf_rne(v6 - bf2f(hb));
            hb = f2bf_rne(v7); ah[7] = (short)hb; al[7] = (short)f2bf_rne(v7 - bf2f(hb));
        }
#pragma unroll
        for (int n = 0; n < 2; ++n) {
            size_t bo = (size_t)(c0 + n * 16) * I_ + kk;
            short8 bh_ = *(const short8*)(wHi + bo);
            short8 bl_ = *(const short8*)(wLo + bo);
            acc[n] = __builtin_amdgcn_mfma_f32_16x16x32_bf16(ah, bh_, acc[n], 0, 0, 0);
            acc[n] = __builtin_amdgcn_mfma_f32_16x16x32_bf16(ah, bl_, acc[n], 0, 0, 0);
            acc[n] = __builtin_amdgcn_mfma_f32_16x16x32_bf16(al, bh_, acc[n], 0, 0, 0);
        }
    }
#pragma unroll
    for (int n = 0; n < 2; ++n)
#pragma unroll
        for (int r = 0; r < 4; ++r) {
            int rr = mt * 64 + mq * 16 + (lane >> 4) * 4 + r;
            int b = rr >> 10, t = rr & 1023;
            gi0[((size_t)t * B_ + b) * G3_ + c0 + n * 16] = acc[n][r];
        }
}

// ---- persistent GRU kernel: 128 blocks x 8 units ---------------------------
// Block grp owns units [grp*8, grp*8+8): 24 real cols/mat, 2 col-tiles.
// w-hi (3 mats x 24 cols) in LDS (144KB, XOR-swizzled); w-lo streamed from
// per-XCD L2 every step (read-only, written once by k_trans_w -> safe cached).
// State: bf16-hi tiled layout (unchanged), sc0sc1 transport (proven).
// Halves vs round 9: state broadcast (16.7MB/step), hot-line replication
// (128 copies), barrier arrivals/pollers (128, 4 groups of 32).
__global__ __launch_bounds__(512, 2) void k_gru_pers(
    const unsigned short* __restrict__ wt,
    const float* __restrict__ gi0,
    const float* __restrict__ b_i, const float* __restrict__ b_h,
    unsigned short* __restrict__ hst,
    unsigned int* __restrict__ bar,
    float* __restrict__ out) {

    __shared__ unsigned short wlds[73728];  // 72 entries x 1024 shorts = 144KB
    __shared__ float red[3 * 32 * 36];      // stride-36: rows 4 apart = 2-way

    const int grp = blockIdx.x;
    const int tid = threadIdx.x, wave = tid >> 6, lane = tid & 63;

    // ---- stage w-hi slice into LDS (once): entry e = m*24 + cl -------------
    for (int idx = tid; idx < 72 * 128; idx += 512) {
        int e = idx >> 7, chunk = idx & 127;
        int m = e / 24, cl = e % 24;
        size_t gcol = (size_t)((cl >> 3) * H_ + grp * 8 + (cl & 7));
        const unsigned short* src = wt + (size_t)(m + 1) * 2 * G3I
                                       + gcol * I_ + (size_t)chunk * 8;
        short8 v = *(const short8*)src;
        int byteoff = (e * 2048 + chunk * 16) ^ ((cl & 7) << 4);
        *(short8*)((char*)wlds + byteoff) = v;
    }

    const int c = lane & 15;
    const int xm = (c & 7) << 4;
    // per (mat m, tile t): LDS byte base + w-lo global base
    int wbh[6];
    const unsigned short* wlop[6];
#pragma unroll
    for (int m = 0; m < 3; ++m) {
        const int cl0 = c;                 // tile0: cols 0-15 (gates 0,1)
        const int cl1 = 16 + (c & 7);      // tile1: cols 16-23 (gate 2; 8-15 dup)
        wbh[m * 2 + 0] = (m * 24 + cl0) * 2048;
        wbh[m * 2 + 1] = (m * 24 + cl1) * 2048;
        wlop[m * 2 + 0] = wt + (size_t)(m + 1) * 2 * G3I + G3I
                        + (size_t)((cl0 >> 3) * H_ + grp * 8 + (cl0 & 7)) * I_;
        wlop[m * 2 + 1] = wt + (size_t)(m + 1) * 2 * G3I + G3I
                        + (size_t)(2 * H_ + grp * 8 + (cl1 & 7)) * I_;
    }
    const char* wbase = (const char*)wlds;

    const int woff = wave * 2048 + lane * 8;  // consumer state offset (shorts)
    // producer: 8 consecutive units = one full 16B unit per b
    const int prodoff = (grp >> 2) * 512 + (((grp & 3) * 16 + (lane & 15)) * 8);
    const int u0 = grp * 8;
    float hp[8];
#pragma unroll
    for (int j = 0; j < 8; ++j) hp[j] = 0.f;

    for (int i = tid; i < 3 * 32 * 36; i += 512) red[i] = 0.f;
    __syncthreads();

#define ISSUE(ks) do { \
    const int off_ = woff + (ks) * 512; \
    st[ks][0] = ld16_sc(A0 + off_); \
    st[ks][1] = ld16_sc(A0 + 16384 + off_); \
    st[ks][2] = ld16_sc(A1 + off_); \
    st[ks][3] = ld16_sc(A1 + 16384 + off_); \
} while (0)

#define IW(buf, ks) do { \
    const int kk_ = wave * 128 + (lane >> 4) * 8 + (ks) * 32; \
    buf[0] = *(const short8*)(wlop[0] + kk_); \
    buf[1] = *(const short8*)(wlop[1] + kk_); \
    buf[2] = *(const short8*)(wlop[2] + kk_); \
    buf[3] = *(const short8*)(wlop[3] + kk_); \
    buf[4] = *(const short8*)(wlop[4] + kk_); \
    buf[5] = *(const short8*)(wlop[5] + kk_); \
} while (0)

#define MFMA1(ks, m, sA, sB, wl) do { \
    short8 w0_ = *(const short8*)(wbase + ((wbh[(m)*2+0] + kb_) ^ xm)); \
    short8 w1_ = *(const short8*)(wbase + ((wbh[(m)*2+1] + kb_) ^ xm)); \
    acc[m][0][0] = __builtin_amdgcn_mfma_f32_16x16x32_bf16(st[ks][sA], w0_, acc[m][0][0], 0, 0, 0); \
    acc[m][0][0] = __builtin_amdgcn_mfma_f32_16x16x32_bf16(st[ks][sA], wl[(m)*2+0], acc[m][0][0], 0, 0, 0); \
    acc[m][0][1] = __builtin_amdgcn_mfma_f32_16x16x32_bf16(st[ks][sB], w0_, acc[m][0][1], 0, 0, 0); \
    acc[m][0][1] = __builtin_amdgcn_mfma_f32_16x16x32_bf16(st[ks][sB], wl[(m)*2+0], acc[m][0][1], 0, 0, 0); \
    acc[m][1][0] = __builtin_amdgcn_mfma_f32_16x16x32_bf16(st[ks][sA], w1_, acc[m][1][0], 0, 0, 0); \
    acc[m][1][0] = __builtin_amdgcn_mfma_f32_16x16x32_bf16(st[ks][sA], wl[(m)*2+1], acc[m][1][0], 0, 0, 0); \
    acc[m][1][1] = __builtin_amdgcn_mfma_f32_16x16x32_bf16(st[ks][sB], w1_, acc[m][1][1], 0, 0, 0); \
    acc[m][1][1] = __builtin_amdgcn_mfma_f32_16x16x32_bf16(st[ks][sB], wl[(m)*2+1], acc[m][1][1], 0, 0, 0); \
} while (0)

#define MG(ks, wl) do { \
    const int kb_ = (wave * 128 + (lane >> 4) * 8 + (ks) * 32) * 2; \
    MFMA1(ks, 0, 0, 1, wl); \
    MFMA1(ks, 1, 0, 1, wl); \
    MFMA1(ks, 2, 2, 3, wl); \
} while (0)

    for (int s = 0; s <= L_; ++s) {
        // gi0 prefetch (plain cached loads; compiler manages their waits)
        float4 g0[6];
#pragma unroll
        for (int j = 0; j < 6; ++j) g0[j] = make_float4(0.f, 0.f, 0.f, 0.f);
        if (wave == 0 && lane < 32 && s < L_) {
            const float* gsrc = gi0 + ((size_t)s * B_ + lane) * G3_;
            g0[0] = *(const float4*)(gsrc + u0);
            g0[1] = *(const float4*)(gsrc + u0 + 4);
            g0[2] = *(const float4*)(gsrc + H_ + u0);
            g0[3] = *(const float4*)(gsrc + H_ + u0 + 4);
            g0[4] = *(const float4*)(gsrc + 2 * H_ + u0);
            g0[5] = *(const float4*)(gsrc + 2 * H_ + u0 + 4);
        }

        const unsigned short* A0 = hst + (size_t)(0 + ((s - 1) & 1)) * 32768; // h0[s-1]
        const unsigned short* A1 = hst + (size_t)(2 + (s & 1)) * 32768;       // h1[s-2]

        floatx4 acc[3][2][2] = {};
        short8 st[4][4];
        short8 wa[6], wb2[6];
        ISSUE(0); ISSUE(1); ISSUE(2); ISSUE(3);   // 16 sc loads (oldest)
        IW(wa, 0); IW(wb2, 1);                     // +12 w-lo (L2)
        VM_WAIT(6);   // all st + wa done (oldest-first completion)
        MG(0, wa);  IW(wa, 2);
        VM_WAIT(6);   // wb2 done
        MG(1, wb2); IW(wb2, 3);
        VM_WAIT(6);   // wa(ks2) done
        MG(2, wa);
        VM_WAIT(0);   // wb2(ks3) + gi0 done
        MG(3, wb2);

        // cross-wave reduce: real cols 0-23; tile1 dup lanes land in 24-31
#pragma unroll
        for (int m = 0; m < 3; ++m)
#pragma unroll
            for (int t = 0; t < 2; ++t)
#pragma unroll
                for (int q = 0; q < 2; ++q)
#pragma unroll
                    for (int r = 0; r < 4; ++r) {
                        int row = q * 16 + (lane >> 4) * 4 + r;
                        atomicAdd(&red[(m * 32 + row) * 36 + t * 16 + c],
                                  acc[m][t][q][r]);
                    }
        __syncthreads();

        // ---- epilogue (act lanes) + reader-side red zeroing ----------------
        if (wave == 0 && lane < 32) {
            const int b = lane;
            float* r0 = &red[b * 36];
            if (s < L_) {
                float hn_[8];
#pragma unroll
                for (int uu = 0; uu < 8; ++uu) {
                    float gr = (&g0[uu >> 2].x)[uu & 3];
                    float gz = (&g0[2 + (uu >> 2)].x)[uu & 3];
                    float gn = (&g0[4 + (uu >> 2)].x)[uu & 3];
                    float vr = gr + b_i[u0 + uu] + r0[uu] + b_h[u0 + uu];
                    float vz = gz + b_i[H_ + u0 + uu] + r0[8 + uu] + b_h[H_ + u0 + uu];
                    float rg = 1.f / (1.f + __expf(-vr));
                    float zg = 1.f / (1.f + __expf(-vz));
                    float ht = tanhf(gn + b_i[2 * H_ + u0 + uu]
                                     + rg * (r0[16 + uu] + b_h[2 * H_ + u0 + uu]));
                    hn_[uu] = zg * hp[uu] + (1.f - zg) * ht;
                    hp[uu] = hn_[uu];
                }
                unsigned long long p0 = 0, p1 = 0;
#pragma unroll
                for (int j = 0; j < 4; ++j) {
                    p0 |= (unsigned long long)f2bf_rne(hn_[j]) << (16 * j);
                    p1 |= (unsigned long long)f2bf_rne(hn_[4 + j]) << (16 * j);
                }
                unsigned short* dst = hst + (size_t)(0 + (s & 1)) * 32768
                                    + (size_t)(b >> 4) * 16384 + prodoff;
                __hip_atomic_store((unsigned long long*)dst, p0,
                                   __ATOMIC_RELAXED, __HIP_MEMORY_SCOPE_AGENT);
                __hip_atomic_store((unsigned long long*)(dst + 4), p1,
                                   __ATOMIC_RELAXED, __HIP_MEMORY_SCOPE_AGENT);
                if (s == L_ - 1) {
                    float* o = out + (size_t)B_ * L_ * H_ + b * H_ + u0;
                    *(float4*)o = make_float4(hn_[0], hn_[1], hn_[2], hn_[3]);
                    *(float4*)(o + 4) = make_float4(hn_[4], hn_[5], hn_[6], hn_[7]);
                }
            }
#pragma unroll
            for (int j = 0; j < 8; ++j)
                *(float4*)&r0[j * 4] = make_float4(0.f, 0.f, 0.f, 0.f);
        } else if (wave == 1 && lane < 32) {
            const int b = lane;
            float* r1 = &red[(32 + b) * 36];
            float* r2 = &red[(64 + b) * 36];
            if (s >= 1) {
                const int t = s - 1;
                const float* bi1 = b_i + G3_;
                const float* bh1 = b_h + G3_;
                float hn_[8];
#pragma unroll
                for (int uu = 0; uu < 8; ++uu) {
                    float vr = r1[uu] + bi1[u0 + uu] + r2[uu] + bh1[u0 + uu];
                    float vz = r1[8 + uu] + bi1[H_ + u0 + uu]
                             + r2[8 + uu] + bh1[H_ + u0 + uu];
                    float rg = 1.f / (1.f + __expf(-vr));
                    float zg = 1.f / (1.f + __expf(-vz));
                    float ht = tanhf(r1[16 + uu] + bi1[2 * H_ + u0 + uu]
                                     + rg * (r2[16 + uu] + bh1[2 * H_ + u0 + uu]));
                    hn_[uu] = zg * hp[uu] + (1.f - zg) * ht;
                    hp[uu] = hn_[uu];
                }
                unsigned long long p0 = 0, p1 = 0;
#pragma unroll
                for (int j = 0; j < 4; ++j) {
                    p0 |= (unsigned long long)f2bf_rne(hn_[j]) << (16 * j);
                    p1 |= (unsigned long long)f2bf_rne(hn_[4 + j]) << (16 * j);
                }
                // state stores FIRST (must drain before arrival); out after
                unsigned short* dst = hst + (size_t)(2 + ((s - 1) & 1)) * 32768
                                    + (size_t)(b >> 4) * 16384 + prodoff;
                __hip_atomic_store((unsigned long long*)dst, p0,
                                   __ATOMIC_RELAXED, __HIP_MEMORY_SCOPE_AGENT);
                __hip_atomic_store((unsigned long long*)(dst + 4), p1,
                                   __ATOMIC_RELAXED, __HIP_MEMORY_SCOPE_AGENT);
                float* o = out + ((size_t)b * L_ + t) * H_ + u0;
                *(float4*)o = make_float4(hn_[0], hn_[1], hn_[2], hn_[3]);
                *(float4*)(o + 4) = make_float4(hn_[4], hn_[5], hn_[6], hn_[7]);
                if (t == L_ - 1) {
                    float* o2 = out + (size_t)B_ * L_ * H_ + (size_t)B_ * H_
                              + b * H_ + u0;
                    *(float4*)o2 = make_float4(hn_[0], hn_[1], hn_[2], hn_[3]);
                    *(float4*)(o2 + 4) = make_float4(hn_[4], hn_[5], hn_[6], hn_[7]);
                }
            }
#pragma unroll
            for (int j = 0; j < 8; ++j) {
                *(float4*)&r1[j * 4] = make_float4(0.f, 0.f, 0.f, 0.f);
                *(float4*)&r2[j * 4] = make_float4(0.f, 0.f, 0.f, 0.f);
            }
        }

        // ---- grid barrier: 128 arrivals, 4 groups of 32 --------------------
        if (s < L_) {
            if (wave == 1) {
                asm volatile("s_waitcnt vmcnt(2)" ::: "memory"); // out may float
            } else {
                asm volatile("s_waitcnt vmcnt(0)" ::: "memory");
            }
            __syncthreads();
            if (tid == 0) {
                const int g = grp >> 5;        // 4 groups of 32 blocks
                __hip_atomic_fetch_add(&bar[g * 256], 1u,
                                       __ATOMIC_RELAXED, __HIP_MEMORY_SCOPE_AGENT);
                if ((grp & 31) == 0) {
                    while (__hip_atomic_load(&bar[g * 256], __ATOMIC_RELAXED,
                                             __HIP_MEMORY_SCOPE_AGENT)
                           < (unsigned)(s + 1) * 32u)
                        __builtin_amdgcn_s_sleep(2);
                    __hip_atomic_fetch_add(&bar[4096], 1u,
                                           __ATOMIC_RELAXED, __HIP_MEMORY_SCOPE_AGENT);
                }
                while (__hip_atomic_load(&bar[4096], __ATOMIC_RELAXED,
                                         __HIP_MEMORY_SCOPE_AGENT)
                       < (unsigned)(s + 1) * 4u)
                    __builtin_amdgcn_s_sleep(2);
            }
            __syncthreads();
        }
    }
#undef ISSUE
#undef IW
#undef MFMA1
#undef MG
}

extern "C" void kernel_launch(void* const* d_in, const int* in_sizes, int n_in,
                              void* d_out, int out_size, void* d_ws, size_t ws_size,
                              hipStream_t stream) {
    const float* x  = (const float*)d_in[0];
    const float* Wi = (const float*)d_in[1];
    const float* bi = (const float*)d_in[2];
    const float* Wh = (const float*)d_in[3];
    const float* bh = (const float*)d_in[4];
    float* out = (float*)d_out;
    char* ws = (char*)d_ws;

    // ws layout (bytes):
    //  [0, 48MB)              wt: 4 mats x {hi,lo} x [3072][1024] bf16
    //  [50331648, +256KB)     hst: 4 regions x 32768 bf16 (h0 s0/s1, h1 s0/s1)
    //  [50855936, +512KB)     bar: barrier counters (spread 1KB apart)
    //  [51380224, +384MB)     gi0: f32 [L][B][3H]
    unsigned short* wt  = (unsigned short*)(ws);
    unsigned short* hst = (unsigned short*)(ws + 50331648);
    unsigned int*   bar = (unsigned int*)(ws + 50855936);
    float*          gi0 = (float*)(ws + 51380224);

    hipMemsetAsync(ws + 50331648, 0, 1048576, stream);
    k_trans_w<<<dim3(768, 4), 256, 0, stream>>>(Wi, Wh, wt);
    k_gi0<<<dim3(512, 48), 512, 0, stream>>>(x, wt, gi0);

    void* args[] = {&wt, &gi0, &bi, &bh, &hst, &bar, &out};
    hipLaunchCooperativeKernel((void*)k_gru_pers, dim3(NBLK), dim3(512), args, 0, stream);
}